// Round 3
// baseline (1378.927 us; speedup 1.0000x reference)
//
#include <hip/hip_runtime.h>
#include <math.h>

#define NIMG 50000
#define NKN  8192
#define BB   32
#define DD   512
#define CC   32
#define RR   16
#define KK   8

// ---------------------------------------------------------------- class lists
__global__ __launch_bounds__(256) void build_lists(const int* __restrict__ labels,
                                                   int n, int* __restrict__ cnt,
                                                   int* __restrict__ list, int stride) {
    int i = blockIdx.x * 256 + threadIdx.x;
    if (i < n) {
        int c = labels[i];
        int pos = atomicAdd(&cnt[c], 1);
        list[c * stride + pos] = i;
    }
}

// ---------------------------------------------------------------- sims = Q @ I^T
// One pass over I; all 32 query rows staged in 64KB LDS.
__global__ __launch_bounds__(256) void sims_kernel(const float* __restrict__ Q,
                                                   const float* __restrict__ I,
                                                   float* __restrict__ S) {
    __shared__ float4 qs[BB * DD / 4];  // 32*128 float4 = 64KB
    for (int i = threadIdx.x; i < BB * DD / 4; i += 256)
        qs[i] = ((const float4*)Q)[i];
    __syncthreads();
    int n = blockIdx.x * 256 + threadIdx.x;
    if (n >= NIMG) return;
    float acc[BB];
#pragma unroll
    for (int b = 0; b < BB; b++) acc[b] = 0.f;
    const float4* row = (const float4*)(I + (size_t)n * DD);
    for (int d4 = 0; d4 < DD / 4; d4++) {
        float4 v = row[d4];
#pragma unroll
        for (int b = 0; b < BB; b++) {
            float4 q = qs[b * (DD / 4) + d4];
            acc[b] += v.x * q.x + v.y * q.y + v.z * q.z + v.w * q.w;
        }
    }
#pragma unroll
    for (int b = 0; b < BB; b++) S[(size_t)b * NIMG + n] = acc[b];
}

// ---------------------------------------------------------------- top-16 images per (b,c)
__global__ __launch_bounds__(256) void topk_img(const float* __restrict__ S,
                                                const int* __restrict__ cnt,
                                                const int* __restrict__ list,
                                                int* __restrict__ t_idx,
                                                float* __restrict__ t_w) {
    int c = blockIdx.x, b = blockIdx.y, tid = threadIdx.x;
    __shared__ float sval[256 * RR];
    __shared__ int   sidx[256 * RR];
    __shared__ float redv[256];
    __shared__ int   redp[256];
    __shared__ float kv[RR];
    __shared__ int   ki[RR];

    float tv[RR]; int ti[RR];
#pragma unroll
    for (int k = 0; k < RR; k++) { tv[k] = -1e30f; ti[k] = 0; }

    int m = cnt[c];
    for (int j = tid; j < m; j += 256) {
        int n = list[c * NIMG + j];
        float v = S[(size_t)b * NIMG + n];
        if (v > tv[RR - 1]) {
            int p = RR - 1;
            while (p > 0 && tv[p - 1] < v) { tv[p] = tv[p - 1]; ti[p] = ti[p - 1]; p--; }
            tv[p] = v; ti[p] = n;
        }
    }
#pragma unroll
    for (int k = 0; k < RR; k++) { sval[tid * RR + k] = tv[k]; sidx[tid * RR + k] = ti[k]; }
    __syncthreads();

    for (int k = 0; k < RR; k++) {
        float bv = -1e30f; int bp = 0;
        for (int j = tid; j < 256 * RR; j += 256)
            if (sval[j] > bv) { bv = sval[j]; bp = j; }
        redv[tid] = bv; redp[tid] = bp;
        __syncthreads();
        for (int s = 128; s > 0; s >>= 1) {
            if (tid < s && redv[tid + s] > redv[tid]) { redv[tid] = redv[tid + s]; redp[tid] = redp[tid + s]; }
            __syncthreads();
        }
        if (tid == 0) { kv[k] = redv[0]; ki[k] = sidx[redp[0]]; sval[redp[0]] = -1e30f; }
        __syncthreads();
    }

    if (tid == 0) {
        float mx = kv[0], s = 0.f, e[RR];
#pragma unroll
        for (int k = 0; k < RR; k++) { e[k] = expf(kv[k] - mx); s += e[k]; }
        float inv = 1.f / s;
        size_t o = ((size_t)(b * CC) + c) * RR;
#pragma unroll
        for (int k = 0; k < RR; k++) { t_w[o + k] = e[k] * inv; t_idx[o + k] = ki[k]; }
    }
}

// ---------------------------------------------------------------- enhanced_images
__global__ __launch_bounds__(256) void img_kernel(const float* __restrict__ Q,
                                                  const float* __restrict__ I,
                                                  const int* __restrict__ t_idx,
                                                  const float* __restrict__ t_w,
                                                  float* __restrict__ out) {
    int c = blockIdx.x, b = blockIdx.y, tid = threadIdx.x;
    __shared__ float w[RR];
    __shared__ int   id[RR];
    if (tid < RR) {
        size_t o = ((size_t)(b * CC) + c) * RR;
        w[tid] = t_w[o + tid]; id[tid] = t_idx[o + tid];
    }
    __syncthreads();
    for (int d = tid; d < DD; d += 256) {
        float acc = 0.f;
#pragma unroll
        for (int r = 0; r < RR; r++) acc += w[r] * I[(size_t)id[r] * DD + d];
        out[((size_t)(b * CC) + c) * DD + d] = 0.5f * (Q[b * DD + d] + acc);
    }
}

// ---------------------------------------------------------------- knowledge retrieval + fusion
__global__ __launch_bounds__(256) void knowledge_kernel(const float* __restrict__ Q,
                                                        const float* __restrict__ I,
                                                        const float* __restrict__ KN,
                                                        const int* __restrict__ kcnt,
                                                        const int* __restrict__ klist,
                                                        const int* __restrict__ t_idx,
                                                        const float* __restrict__ t_w,
                                                        float* __restrict__ outk) {
    int c = blockIdx.x, b = blockIdx.y, tid = threadIdx.x;
    __shared__ float irow[DD];
    __shared__ float sv[256 * KK];
    __shared__ int   si[256 * KK];
    __shared__ float redv[256];
    __shared__ int   redp[256];
    __shared__ float kv[KK];
    __shared__ int   ki[KK];
    __shared__ float kw[KK];
    __shared__ float s_iw[RR];
    __shared__ int   s_ii[RR];

    if (tid < RR) {
        size_t o = ((size_t)(b * CC) + c) * RR;
        s_iw[tid] = t_w[o + tid]; s_ii[tid] = t_idx[o + tid];
    }
    int m = kcnt[c];
    float acc0 = 0.f, acc1 = 0.f;

    for (int r = 0; r < RR; r++) {
        __syncthreads();
        int irn = s_ii[r];
        for (int d = tid; d < DD; d += 256) irow[d] = I[(size_t)irn * DD + d];
        __syncthreads();

        float tv[KK]; int ti[KK];
#pragma unroll
        for (int k = 0; k < KK; k++) { tv[k] = -1e30f; ti[k] = 0; }

        for (int j = tid; j < m; j += 256) {
            int kn = klist[c * NKN + j];
            const float4* kr = (const float4*)(KN + (size_t)kn * DD);
            const float4* ir = (const float4*)irow;
            float dx = 0.f, dy = 0.f, dz = 0.f, dw = 0.f;
            for (int d4 = 0; d4 < DD / 4; d4++) {
                float4 v = kr[d4]; float4 u = ir[d4];
                dx += v.x * u.x; dy += v.y * u.y; dz += v.z * u.z; dw += v.w * u.w;
            }
            float dot = (dx + dy) + (dz + dw);
            if (dot > tv[KK - 1]) {
                int p = KK - 1;
                while (p > 0 && tv[p - 1] < dot) { tv[p] = tv[p - 1]; ti[p] = ti[p - 1]; p--; }
                tv[p] = dot; ti[p] = kn;
            }
        }
#pragma unroll
        for (int k = 0; k < KK; k++) { sv[tid * KK + k] = tv[k]; si[tid * KK + k] = ti[k]; }
        __syncthreads();

        for (int k = 0; k < KK; k++) {
            float bv = -1e30f; int bp = 0;
            for (int j = tid; j < 256 * KK; j += 256)
                if (sv[j] > bv) { bv = sv[j]; bp = j; }
            redv[tid] = bv; redp[tid] = bp;
            __syncthreads();
            for (int s = 128; s > 0; s >>= 1) {
                if (tid < s && redv[tid + s] > redv[tid]) { redv[tid] = redv[tid + s]; redp[tid] = redp[tid + s]; }
                __syncthreads();
            }
            if (tid == 0) { kv[k] = redv[0]; ki[k] = si[redp[0]]; sv[redp[0]] = -1e30f; }
            __syncthreads();
        }

        if (tid == 0) {
            float mx = kv[0], s = 0.f, e[KK];
#pragma unroll
            for (int k = 0; k < KK; k++) { e[k] = expf(kv[k] - mx); s += e[k]; }
            float inv = 1.f / s;
#pragma unroll
            for (int k = 0; k < KK; k++) kw[k] = e[k] * inv;
        }
        __syncthreads();

        float wr = s_iw[r];
        float a0 = 0.f, a1 = 0.f;
#pragma unroll
        for (int k = 0; k < KK; k++) {
            const float* krow = KN + (size_t)ki[k] * DD;
            a0 += kw[k] * krow[tid];
            a1 += kw[k] * krow[tid + 256];
        }
        acc0 += wr * a0; acc1 += wr * a1;
    }

    size_t o = ((size_t)(b * CC) + c) * DD;
    outk[o + tid]       = 0.5f * (Q[b * DD + tid] + acc0);
    outk[o + tid + 256] = 0.5f * (Q[b * DD + tid + 256] + acc1);
}

// ---------------------------------------------------------------- launch
extern "C" void kernel_launch(void* const* d_in, const int* in_sizes, int n_in,
                              void* d_out, int out_size, void* d_ws, size_t ws_size,
                              hipStream_t stream) {
    const float* Q  = (const float*)d_in[0];
    const float* I  = (const float*)d_in[1];
    const float* KN = (const float*)d_in[2];
    const int* ilab = (const int*)d_in[3];
    const int* klab = (const int*)d_in[4];

    char* ws = (char*)d_ws;
    float* S        = (float*)ws;  ws += (size_t)BB * NIMG * 4;
    int*   img_list = (int*)ws;    ws += (size_t)CC * NIMG * 4;
    int*   kn_list  = (int*)ws;    ws += (size_t)CC * NKN * 4;
    int*   t_idx    = (int*)ws;    ws += (size_t)BB * CC * RR * 4;
    float* t_w      = (float*)ws;  ws += (size_t)BB * CC * RR * 4;
    int*   img_cnt  = (int*)ws;    ws += CC * 4;
    int*   kn_cnt   = (int*)ws;    ws += CC * 4;

    float* out_img = (float*)d_out;
    float* out_kn  = out_img + (size_t)BB * CC * DD;

    hipMemsetAsync(img_cnt, 0, 2 * CC * 4, stream);  // img_cnt + kn_cnt contiguous

    build_lists<<<(NIMG + 255) / 256, 256, 0, stream>>>(ilab, NIMG, img_cnt, img_list, NIMG);
    build_lists<<<(NKN  + 255) / 256, 256, 0, stream>>>(klab, NKN,  kn_cnt,  kn_list,  NKN);
    sims_kernel<<<(NIMG + 255) / 256, 256, 0, stream>>>(Q, I, S);
    topk_img<<<dim3(CC, BB), 256, 0, stream>>>(S, img_cnt, img_list, t_idx, t_w);
    img_kernel<<<dim3(CC, BB), 256, 0, stream>>>(Q, I, t_idx, t_w, (float*)d_out);
    knowledge_kernel<<<dim3(CC, BB), 256, 0, stream>>>(Q, I, KN, kn_cnt, kn_list, t_idx, t_w, out_kn);
}

// Round 4
// 461.029 us; speedup vs baseline: 2.9910x; 2.9910x over previous
//
#include <hip/hip_runtime.h>
#include <math.h>

#define NIMG 50000
#define NKN  8192
#define BB   32
#define DD   512
#define CC   32
#define RR   16
#define KK   8
#define MMAX 384   // max class-bucket size supported (mean 256, sd ~15.7; 384 = +8 sd)

// ---------------------------------------------------------------- class lists
__global__ __launch_bounds__(256) void build_lists(const int* __restrict__ labels,
                                                   int n, int* __restrict__ cnt,
                                                   int* __restrict__ list, int stride) {
    int i = blockIdx.x * 256 + threadIdx.x;
    if (i < n) {
        int c = labels[i];
        int pos = atomicAdd(&cnt[c], 1);
        list[c * stride + pos] = i;
    }
}

// ---------------------------------------------------------------- sims = Q @ I^T
__global__ __launch_bounds__(256) void sims_kernel(const float* __restrict__ Q,
                                                   const float* __restrict__ I,
                                                   float* __restrict__ S) {
    __shared__ float4 qs[BB * DD / 4];  // 64KB
    for (int i = threadIdx.x; i < BB * DD / 4; i += 256)
        qs[i] = ((const float4*)Q)[i];
    __syncthreads();
    int n = blockIdx.x * 256 + threadIdx.x;
    if (n >= NIMG) return;
    float acc[BB];
#pragma unroll
    for (int b = 0; b < BB; b++) acc[b] = 0.f;
    const float4* row = (const float4*)(I + (size_t)n * DD);
    for (int d4 = 0; d4 < DD / 4; d4++) {
        float4 v = row[d4];
#pragma unroll
        for (int b = 0; b < BB; b++) {
            float4 q = qs[b * (DD / 4) + d4];
            acc[b] += v.x * q.x + v.y * q.y + v.z * q.z + v.w * q.w;
        }
    }
#pragma unroll
    for (int b = 0; b < BB; b++) S[(size_t)b * NIMG + n] = acc[b];
}

// ---------------------------------------------------------------- top-16 images per (b,c)
__global__ __launch_bounds__(256) void topk_img(const float* __restrict__ S,
                                                const int* __restrict__ cnt,
                                                const int* __restrict__ list,
                                                int* __restrict__ t_idx,
                                                float* __restrict__ t_w) {
    int c = blockIdx.x, b = blockIdx.y, tid = threadIdx.x;
    __shared__ float sval[256 * RR];
    __shared__ int   sidx[256 * RR];
    __shared__ float redv[256];
    __shared__ int   redp[256];
    __shared__ float kv[RR];
    __shared__ int   ki[RR];

    float tv[RR]; int ti[RR];
#pragma unroll
    for (int k = 0; k < RR; k++) { tv[k] = -1e30f; ti[k] = 0; }

    int m = cnt[c];
    for (int j = tid; j < m; j += 256) {
        int n = list[c * NIMG + j];
        float v = S[(size_t)b * NIMG + n];
        if (v > tv[RR - 1]) {
            int p = RR - 1;
            while (p > 0 && tv[p - 1] < v) { tv[p] = tv[p - 1]; ti[p] = ti[p - 1]; p--; }
            tv[p] = v; ti[p] = n;
        }
    }
#pragma unroll
    for (int k = 0; k < RR; k++) { sval[tid * RR + k] = tv[k]; sidx[tid * RR + k] = ti[k]; }
    __syncthreads();

    for (int k = 0; k < RR; k++) {
        float bv = -1e30f; int bp = 0;
        for (int j = tid; j < 256 * RR; j += 256)
            if (sval[j] > bv) { bv = sval[j]; bp = j; }
        redv[tid] = bv; redp[tid] = bp;
        __syncthreads();
        for (int s = 128; s > 0; s >>= 1) {
            if (tid < s && redv[tid + s] > redv[tid]) { redv[tid] = redv[tid + s]; redp[tid] = redp[tid + s]; }
            __syncthreads();
        }
        if (tid == 0) { kv[k] = redv[0]; ki[k] = sidx[redp[0]]; sval[redp[0]] = -1e30f; }
        __syncthreads();
    }

    if (tid == 0) {
        float mx = kv[0], s = 0.f, e[RR];
#pragma unroll
        for (int k = 0; k < RR; k++) { e[k] = expf(kv[k] - mx); s += e[k]; }
        float inv = 1.f / s;
        size_t o = ((size_t)(b * CC) + c) * RR;
#pragma unroll
        for (int k = 0; k < RR; k++) { t_w[o + k] = e[k] * inv; t_idx[o + k] = ki[k]; }
    }
}

// ---------------------------------------------------------------- enhanced_images
__global__ __launch_bounds__(256) void img_kernel(const float* __restrict__ Q,
                                                  const float* __restrict__ I,
                                                  const int* __restrict__ t_idx,
                                                  const float* __restrict__ t_w,
                                                  float* __restrict__ out) {
    int c = blockIdx.x, b = blockIdx.y, tid = threadIdx.x;
    __shared__ float w[RR];
    __shared__ int   id[RR];
    if (tid < RR) {
        size_t o = ((size_t)(b * CC) + c) * RR;
        w[tid] = t_w[o + tid]; id[tid] = t_idx[o + tid];
    }
    __syncthreads();
    for (int d = tid; d < DD; d += 256) {
        float acc = 0.f;
#pragma unroll
        for (int r = 0; r < RR; r++) acc += w[r] * I[(size_t)id[r] * DD + d];
        out[((size_t)(b * CC) + c) * DD + d] = 0.5f * (Q[b * DD + d] + acc);
    }
}

// ---------------------------------------------------------------- knowledge v2
// One block per (b,c). Single pass over the class's KN rows scores all 16
// retrieved image rows at once (thread<->KN-row, 16 accs vs LDS-broadcast
// image tiles). Per-r top-8 is wave-local (shuffle argmax, zero barriers).
__global__ __launch_bounds__(256) void knowledge_kernel(const float* __restrict__ Q,
                                                        const float* __restrict__ I,
                                                        const float* __restrict__ KN,
                                                        const int* __restrict__ kcnt,
                                                        const int* __restrict__ klist,
                                                        const int* __restrict__ t_idx,
                                                        const float* __restrict__ t_w,
                                                        float* __restrict__ outk) {
    int c = blockIdx.x, b = blockIdx.y, tid = threadIdx.x;
    int lane = tid & 63, wave = tid >> 6;

    __shared__ float4 simg[RR][DD / 4];   // 32 KB: 16 retrieved image rows
    __shared__ float  sc[RR][MMAX];       // 24 KB: scores per (r, class-row)
    __shared__ int    jrow[MMAX];         // class-row j -> global KN row index
    __shared__ float  s_iw[RR];
    __shared__ int    s_ii[RR];
    __shared__ float  wgt[RR][KK];        // combined weights iw_r * softmax_k
    __shared__ int    kidx[RR][KK];       // selected KN row indices

    if (tid < RR) {
        size_t o = ((size_t)(b * CC) + c) * RR;
        s_iw[tid] = t_w[o + tid]; s_ii[tid] = t_idx[o + tid];
    }
    __syncthreads();

    // stage the 16 retrieved image rows (2048 float4, 8 per thread)
    for (int i = tid; i < RR * DD / 4; i += 256) {
        int r = i / (DD / 4), d4 = i % (DD / 4);
        simg[r][d4] = ((const float4*)(I + (size_t)s_ii[r] * DD))[d4];
    }
    int m = kcnt[c]; if (m > MMAX) m = MMAX;
    __syncthreads();

    // ---- scoring: each thread owns KN class-rows j = tid (+256)
    for (int j = tid; j < MMAX; j += 256) {
        if (j < m) {
            int row = klist[c * NKN + j];
            jrow[j] = row;
            const float4* kr = (const float4*)(KN + (size_t)row * DD);
            float acc[RR];
#pragma unroll
            for (int r = 0; r < RR; r++) acc[r] = 0.f;
            for (int d4 = 0; d4 < DD / 4; d4++) {
                float4 v = kr[d4];
#pragma unroll
                for (int r = 0; r < RR; r++) {
                    float4 u = simg[r][d4];   // wave-uniform -> LDS broadcast
                    acc[r] += v.x * u.x + v.y * u.y + v.z * u.z + v.w * u.w;
                }
            }
#pragma unroll
            for (int r = 0; r < RR; r++) sc[r][j] = acc[r];
        } else {
            jrow[j] = 0;
#pragma unroll
            for (int r = 0; r < RR; r++) sc[r][j] = -1e30f;
        }
    }
    __syncthreads();

    // ---- per-r top-8 + softmax, wave-local (wave w handles r = w, w+4, w+8, w+12)
    for (int rr = 0; rr < RR / 4; rr++) {
        int r = rr * 4 + wave;
        float lv[6]; int lj[6];
#pragma unroll
        for (int t = 0; t < 6; t++) { lv[t] = sc[r][lane + t * 64]; lj[t] = lane + t * 64; }
        unsigned used = 0;
        float kvv[KK]; int kjj[KK];
#pragma unroll
        for (int k = 0; k < KK; k++) {
            float mv = -1e30f; int mj = 0x7fffffff; int mt = 0;
#pragma unroll
            for (int t = 0; t < 6; t++) {
                bool avail = !(used & (1u << t));
                if (avail && (lv[t] > mv || (lv[t] == mv && lj[t] < mj))) {
                    mv = lv[t]; mj = lj[t]; mt = t;
                }
            }
            int cj = mj;  // my local candidate
            // wave argmax, lexicographic (val desc, j asc) -> unique winner
            for (int off = 32; off > 0; off >>= 1) {
                float ov = __shfl_xor(mv, off);
                int   oj = __shfl_xor(mj, off);
                if (ov > mv || (ov == mv && oj < mj)) { mv = ov; mj = oj; }
            }
            if (cj == mj) used |= (1u << mt);  // owner retires it
            kvv[k] = mv; kjj[k] = mj;
        }
        // softmax (kvv[0] is the max), fold in image weight; lane 0 publishes
        if (lane == 0) {
            float e[KK], s = 0.f;
#pragma unroll
            for (int k = 0; k < KK; k++) { e[k] = expf(kvv[k] - kvv[0]); s += e[k]; }
            float wr = s_iw[r] / s;
#pragma unroll
            for (int k = 0; k < KK; k++) {
                wgt[r][k] = e[k] * wr;
                kidx[r][k] = jrow[kjj[k]];
            }
        }
    }
    __syncthreads();

    // ---- gather-accumulate: out = 0.5*(Q + sum over 128 (r,k) pairs)
    float acc0 = 0.f, acc1 = 0.f;
#pragma unroll 4
    for (int p = 0; p < RR * KK; p++) {
        int r = p >> 3, k = p & 7;
        float w = wgt[r][k];
        const float* krow = KN + (size_t)kidx[r][k] * DD;
        acc0 += w * krow[tid];
        acc1 += w * krow[tid + 256];
    }
    size_t o = ((size_t)(b * CC) + c) * DD;
    outk[o + tid]       = 0.5f * (Q[b * DD + tid] + acc0);
    outk[o + tid + 256] = 0.5f * (Q[b * DD + tid + 256] + acc1);
}

// ---------------------------------------------------------------- launch
extern "C" void kernel_launch(void* const* d_in, const int* in_sizes, int n_in,
                              void* d_out, int out_size, void* d_ws, size_t ws_size,
                              hipStream_t stream) {
    const float* Q  = (const float*)d_in[0];
    const float* I  = (const float*)d_in[1];
    const float* KN = (const float*)d_in[2];
    const int* ilab = (const int*)d_in[3];
    const int* klab = (const int*)d_in[4];

    char* ws = (char*)d_ws;
    float* S        = (float*)ws;  ws += (size_t)BB * NIMG * 4;
    int*   img_list = (int*)ws;    ws += (size_t)CC * NIMG * 4;
    int*   kn_list  = (int*)ws;    ws += (size_t)CC * NKN * 4;
    int*   t_idx    = (int*)ws;    ws += (size_t)BB * CC * RR * 4;
    float* t_w      = (float*)ws;  ws += (size_t)BB * CC * RR * 4;
    int*   img_cnt  = (int*)ws;    ws += CC * 4;
    int*   kn_cnt   = (int*)ws;    ws += CC * 4;

    float* out_img = (float*)d_out;
    float* out_kn  = out_img + (size_t)BB * CC * DD;

    hipMemsetAsync(img_cnt, 0, 2 * CC * 4, stream);  // img_cnt + kn_cnt contiguous

    build_lists<<<(NIMG + 255) / 256, 256, 0, stream>>>(ilab, NIMG, img_cnt, img_list, NIMG);
    build_lists<<<(NKN  + 255) / 256, 256, 0, stream>>>(klab, NKN,  kn_cnt,  kn_list,  NKN);
    sims_kernel<<<(NIMG + 255) / 256, 256, 0, stream>>>(Q, I, S);
    topk_img<<<dim3(CC, BB), 256, 0, stream>>>(S, img_cnt, img_list, t_idx, t_w);
    img_kernel<<<dim3(CC, BB), 256, 0, stream>>>(Q, I, t_idx, t_w, (float*)d_out);
    knowledge_kernel<<<dim3(CC, BB), 256, 0, stream>>>(Q, I, KN, kn_cnt, kn_list, t_idx, t_w, out_kn);
}